// Round 8
// baseline (323.126 us; speedup 1.0000x reference)
//
#include <hip/hip_runtime.h>
#include <math.h>

#define EMBED  1024
#define DSTATE 16
#define DCONV  4
#define DTRANK 64
#define BB     2
#define TT     2048
#define M_TOK  (BB*TT)      // 4096 token rows
#define NCHUNK 64
#define CLEN   (TT/NCHUNK)  // 32
#define NMID   1152         // 1024 delta + 32 B/C + 96 pad

typedef __attribute__((ext_vector_type(8))) __bf16 bf16x8;
typedef __attribute__((ext_vector_type(4))) float floatx4;

__device__ __forceinline__ float silu_f(float x) {
    return x / (1.0f + __expf(-x));
}
// fast softplus: no log1pf libcall; exact to ~1e-7 (plenty for bf16 out)
__device__ __forceinline__ float softplus_f(float x) {
    return (x > 15.0f) ? x : __logf(1.0f + __expf(x));
}
__device__ __forceinline__ unsigned short f2bf(float f) {
    union { float f; unsigned int u; } v; v.f = f;
    unsigned int u = v.u;
    return (unsigned short)((u + 0x7fffu + ((u >> 16) & 1u)) >> 16);
}
__device__ __forceinline__ float bf2f(unsigned short s) {
    union { unsigned int u; float f; } v; v.u = ((unsigned int)s) << 16;
    return v.f;
}
__device__ __forceinline__ void async16(unsigned short* lds, const unsigned short* g) {
    __builtin_amdgcn_global_load_lds(
        (const __attribute__((address_space(1))) unsigned int*)g,
        (__attribute__((address_space(3))) unsigned int*)lds, 16, 0, 0);
}

// decode helper for the 2x2-wave 128x128 tile
#define GEMM_DECODE \
    const int tid = threadIdx.x; const int wid = tid >> 6; \
    const int lane = tid & 63; \
    const int wm = wid >> 1, wn = wid & 1; \
    const int lr = lane & 15; const int lq = lane >> 4;

// ---------------------------------------------------------------------------
// MFMA core: 128x128 tile, BK=32, 256 thr = 4 waves (2x2), 4x4 16x16x32/wave.
// XOR-swizzled LDS (verified R6: SQ_LDS_BANK_CONFLICT -> 0).
// ---------------------------------------------------------------------------
__device__ __forceinline__ void gemm_acc(
    const unsigned short* __restrict__ A, int lda,
    const unsigned short* __restrict__ W, int ldw,
    int m0, int n0, int k0, int klen, floatx4 (&acc)[4][4])
{
    __shared__ unsigned short As[128 * 32];
    __shared__ unsigned short Ws[128 * 32];
    GEMM_DECODE;
    const int l0 = tid,       row0 = l0 >> 2;
    const int l1 = tid + 256, row1 = l1 >> 2;
    const int kc0 = (((l0 & 3) ^ ((row0 >> 1) & 3)) * 8);
    const int kc1 = (((l1 & 3) ^ ((row1 >> 1) & 3)) * 8);

    for (int kt = k0; kt < k0 + klen; kt += 32) {
        async16(&As[l0 * 8], A + (size_t)(m0 + row0) * lda + kt + kc0);
        async16(&As[l1 * 8], A + (size_t)(m0 + row1) * lda + kt + kc1);
        async16(&Ws[l0 * 8], W + (size_t)(n0 + row0) * ldw + kt + kc0);
        async16(&Ws[l1 * 8], W + (size_t)(n0 + row1) * ldw + kt + kc1);
        __syncthreads();

        bf16x8 af[4], bfr[4];
        #pragma unroll
        for (int i = 0; i < 4; ++i) {
            int ra = wm * 64 + i * 16 + lr;
            af[i] = *(const bf16x8*)&As[ra * 32 + ((lq ^ ((ra >> 1) & 3)) * 8)];
        }
        #pragma unroll
        for (int i = 0; i < 4; ++i) {
            int rb = wn * 64 + i * 16 + lr;
            bfr[i] = *(const bf16x8*)&Ws[rb * 32 + ((lq ^ ((rb >> 1) & 3)) * 8)];
        }

        #pragma unroll
        for (int mi = 0; mi < 4; ++mi)
            #pragma unroll
            for (int ni = 0; ni < 4; ++ni)
                acc[mi][ni] = __builtin_amdgcn_mfma_f32_16x16x32_bf16(
                    af[mi], bfr[ni], acc[mi][ni], 0, 0, 0);
        __syncthreads();
    }
}

// ---------------------------------------------------------------------------
// in_proj: x @ in_w^T + b.  n<1024 -> xrb bf16 (conv input);
//          n>=1024 -> gate = silu(res) bf16.  grid (32, 16)
// ---------------------------------------------------------------------------
__global__ __launch_bounds__(256)
void gemm_in(const unsigned short* __restrict__ A,
             const unsigned short* __restrict__ W,
             const float* __restrict__ bias,
             unsigned short* __restrict__ xrb, unsigned short* __restrict__ gate)
{
    floatx4 acc[4][4] = {};
    const int m0 = blockIdx.x * 128, n0 = blockIdx.y * 128;
    gemm_acc(A, 2 * EMBED, W, EMBED, m0, n0, 0, EMBED, acc);
    GEMM_DECODE;
    #pragma unroll
    for (int mi = 0; mi < 4; ++mi)
        #pragma unroll
        for (int ni = 0; ni < 4; ++ni) {
            int nb = n0 + wn * 64 + ni * 16 + lr;
            #pragma unroll
            for (int r = 0; r < 4; ++r) {
                int m = m0 + wm * 64 + mi * 16 + lq * 4 + r;
                float v = acc[mi][ni][r] + bias[nb];
                if (nb < EMBED) xrb[(size_t)m * EMBED + nb] = f2bf(v);
                else gate[(size_t)m * EMBED + nb - EMBED] = f2bf(silu_f(v));
            }
        }
}

// ---------------------------------------------------------------------------
// Wfuse precompute: Wfuse[d,k] = sum_r dt_w[d,r] * xp_w[r,k]  (r<64, k<1024)
// -> wmid rows 0..1023 (bf16).  Also bias_mid[d] = dt_w[d,:]@xp_b[0:64]+dt_b[d]
// and bias_mid[1024..1151] tail.  grid 256 x 256thr; thread = (dloc 0-3, kq 0-63)
// ---------------------------------------------------------------------------
__global__ __launch_bounds__(256)
void wfuse_kernel(const float* __restrict__ dt_w, const float* __restrict__ xp_w,
                  const float* __restrict__ xp_b, const float* __restrict__ dt_b,
                  unsigned short* __restrict__ wmid, float* __restrict__ bias_mid)
{
    __shared__ float dtl[4][64];
    const int t = threadIdx.x;
    dtl[t >> 6][t & 63] = dt_w[(size_t)(blockIdx.x * 4 + (t >> 6)) * DTRANK + (t & 63)];
    __syncthreads();
    const int dloc = t >> 6, kq = t & 63;
    const int d = blockIdx.x * 4 + dloc;

    #pragma unroll
    for (int j = 0; j < 4; ++j) {
        float4 acc = {0.f, 0.f, 0.f, 0.f};
        const int kb = j * 256 + kq * 4;
        for (int r = 0; r < 64; ++r) {
            float4 xv = *(const float4*)&xp_w[(size_t)r * EMBED + kb];
            float s = dtl[dloc][r];
            acc.x = fmaf(s, xv.x, acc.x);
            acc.y = fmaf(s, xv.y, acc.y);
            acc.z = fmaf(s, xv.z, acc.z);
            acc.w = fmaf(s, xv.w, acc.w);
        }
        ushort4 o = { f2bf(acc.x), f2bf(acc.y), f2bf(acc.z), f2bf(acc.w) };
        *(ushort4*)&wmid[(size_t)d * EMBED + kb] = o;
    }

    if (kq == 0) {
        float b = dt_b[d];
        for (int r = 0; r < 64; ++r) b = fmaf(dtl[dloc][r], xp_b[r], b);
        bias_mid[d] = b;
    }
    if (blockIdx.x == 0 && t < 128)
        bias_mid[1024 + t] = (t < 32) ? xp_b[DTRANK + t] : 0.f;
}

// ---------------------------------------------------------------------------
// fused mid GEMM: xc @ wmid^T + bias_mid.  grid (32, 9), K=1024.
//   nb < 1024  -> delta = softplus -> dltb bf16
//   1024..1055 -> B/C fp32 -> bc[m, 0:32]  (B = 0:16, C = 16:32)
//   else pad, discarded
// ---------------------------------------------------------------------------
__global__ __launch_bounds__(256)
void gemm_mid(const unsigned short* __restrict__ A,
              const unsigned short* __restrict__ W,
              const float* __restrict__ bias_mid,
              unsigned short* __restrict__ dltb, float* __restrict__ bc)
{
    floatx4 acc[4][4] = {};
    const int m0 = blockIdx.x * 128, n0 = blockIdx.y * 128;
    gemm_acc(A, EMBED, W, EMBED, m0, n0, 0, EMBED, acc);
    GEMM_DECODE;
    #pragma unroll
    for (int mi = 0; mi < 4; ++mi)
        #pragma unroll
        for (int ni = 0; ni < 4; ++ni) {
            int nb = n0 + wn * 64 + ni * 16 + lr;
            float bb = bias_mid[nb];
            #pragma unroll
            for (int r = 0; r < 4; ++r) {
                int m = m0 + wm * 64 + mi * 16 + lq * 4 + r;
                float v = acc[mi][ni][r] + bb;
                if (nb < 1024) dltb[(size_t)m * EMBED + nb] = f2bf(softplus_f(v));
                else if (nb < 1056) bc[(size_t)m * 32 + nb - 1024] = v;
            }
        }
}

// ---------------------------------------------------------------------------
// fused out+skip: [yb|x] @ [ow|sw]^T + ob + sb.  grid (32, 8), K=2048
// ---------------------------------------------------------------------------
__global__ __launch_bounds__(256)
void gemm_out(const unsigned short* __restrict__ A,
              const unsigned short* __restrict__ W,
              const float* __restrict__ bias, const float* __restrict__ bias2,
              float* __restrict__ C)
{
    floatx4 acc[4][4] = {};
    const int m0 = blockIdx.x * 128, n0 = blockIdx.y * 128;
    gemm_acc(A, 2 * EMBED, W, 2 * EMBED, m0, n0, 0, 2 * EMBED, acc);
    GEMM_DECODE;
    #pragma unroll
    for (int mi = 0; mi < 4; ++mi)
        #pragma unroll
        for (int ni = 0; ni < 4; ++ni) {
            int nb = n0 + wn * 64 + ni * 16 + lr;
            float bb = bias[nb] + bias2[nb];
            #pragma unroll
            for (int r = 0; r < 4; ++r) {
                int m = m0 + wm * 64 + mi * 16 + lq * 4 + r;
                C[(size_t)m * EMBED + nb] = acc[mi][ni][r] + bb;
            }
        }
}

// ---------------------------------------------------------------------------
// single fused pack kernel (float4 units):
//   [0, SA)      in_w -> inwb
//   [SA, SB)     [out_w|skip_w] -> wcat
//   [SB, SC)     x -> Acat[:, 1024:2048]
//   [SC, SD)     wmid rows 1024..1151: 32 B/C rows from xp_w[64:96], 96 zero
// ---------------------------------------------------------------------------
#define SA 524288
#define SB (SA + 524288)
#define SC (SB + 1048576)
#define SD (SC + 32768)

__global__ __launch_bounds__(256)
void cvt_pack(const float* __restrict__ in_w, const float* __restrict__ xp_w,
              const float* __restrict__ ow, const float* __restrict__ sw,
              const float* __restrict__ x,
              unsigned short* __restrict__ inwb, unsigned short* __restrict__ wcat,
              unsigned short* __restrict__ Acat, unsigned short* __restrict__ wmid)
{
    int j = blockIdx.x * 256 + threadIdx.x;
    if (j >= SD) return;
    float4 v = {0.f, 0.f, 0.f, 0.f};
    unsigned short* dst;
    if (j < SA) {
        v = *(const float4*)&in_w[j * 4];
        dst = &inwb[j * 4];
    } else if (j < SB) {
        int i = (j - SA) * 4;
        int n = i >> 11, k = i & 2047;
        v = *(const float4*)((k < EMBED) ? &ow[(size_t)n * EMBED + k]
                                         : &sw[(size_t)n * EMBED + (k - EMBED)]);
        dst = &wcat[i];
    } else if (j < SC) {
        int i = (j - SB) * 4;
        int m = i >> 10, k = i & 1023;
        v = *(const float4*)&x[i];
        dst = &Acat[(size_t)m * 2 * EMBED + EMBED + k];
    } else {
        int i = (j - SC) * 4;          // over 128*1024
        int row = i >> 10, k = i & 1023;
        if (row < 32) v = *(const float4*)&xp_w[(size_t)(DTRANK + row) * EMBED + k];
        dst = &wmid[(size_t)(1024 + row) * EMBED + k];
    }
    ushort4 o = { f2bf(v.x), f2bf(v.y), f2bf(v.z), f2bf(v.w) };
    *(ushort4*)dst = o;
}

// ---------------------------------------------------------------------------
// depthwise causal conv1d (k=4) + bias + SiLU -> xc bf16; 4 channels/thread
// ---------------------------------------------------------------------------
__global__ __launch_bounds__(256)
void conv_silu(const unsigned short* __restrict__ xrb,
               const float* __restrict__ conv_w,
               const float* __restrict__ conv_b,
               unsigned short* __restrict__ xcb)
{
    int idx = blockIdx.x * 256 + threadIdx.x;     // over B*T*D/4 = 1M
    if (idx >= BB * TT * EMBED / 4) return;
    int dq = idx & (EMBED / 4 - 1);
    int t  = (idx >> 8) & (TT - 1);
    int b  = idx >> 19;
    int d  = dq * 4;

    float4 cw0 = *(const float4*)&conv_w[(d + 0) * 4];
    float4 cw1 = *(const float4*)&conv_w[(d + 1) * 4];
    float4 cw2 = *(const float4*)&conv_w[(d + 2) * 4];
    float4 cw3 = *(const float4*)&conv_w[(d + 3) * 4];
    float4 s   = *(const float4*)&conv_b[d];

    const float* w0 = (const float*)&cw0;
    const float* w1 = (const float*)&cw1;
    const float* w2 = (const float*)&cw2;
    const float* w3 = (const float*)&cw3;

    #pragma unroll
    for (int jj = 0; jj < 4; ++jj) {
        int tr = t - 3 + jj;
        if (tr >= 0) {
            ushort4 u = *(const ushort4*)&xrb[(size_t)(b * TT + tr) * EMBED + d];
            s.x = fmaf(w0[jj], bf2f(u.x), s.x);
            s.y = fmaf(w1[jj], bf2f(u.y), s.y);
            s.z = fmaf(w2[jj], bf2f(u.z), s.z);
            s.w = fmaf(w3[jj], bf2f(u.w), s.w);
        }
    }
    ushort4 o = { f2bf(silu_f(s.x)), f2bf(silu_f(s.y)),
                  f2bf(silu_f(s.z)), f2bf(silu_f(s.w)) };
    *(ushort4*)&xcb[(size_t)(b * TT + t) * EMBED + d] = o;
}

// ---------------------------------------------------------------------------
// Scan pass A: thread per (b,chunk,d), 16 states in regs. B from bc[m,0:16].
// ---------------------------------------------------------------------------
__global__ __launch_bounds__(256)
void scan_chunk(const unsigned short* __restrict__ deltab,
                const unsigned short* __restrict__ xcb,
                const float* __restrict__ bc,
                const float* __restrict__ A_log,
                float* __restrict__ hout,
                float* __restrict__ Ssum)
{
    __shared__ float Bs[CLEN][DSTATE];
    const int tid = threadIdx.x;
    const int blk = blockIdx.x;
    const int dg = blk & 3, chunk = (blk >> 2) & (NCHUNK - 1), b = blk >> 8;
    const int d = dg * 256 + tid;
    const int t0 = chunk * CLEN;

    for (int i = tid; i < CLEN * DSTATE; i += 256) {
        int t = i >> 4, n = i & 15;
        Bs[t][n] = bc[(size_t)(b * TT + t0 + t) * 32 + n];
    }
    __syncthreads();

    float An[DSTATE];
    #pragma unroll
    for (int n = 0; n < DSTATE; ++n) An[n] = -__expf(A_log[n]);

    float h[DSTATE] = {};
    float S = 0.f;
    for (int t = 0; t < CLEN; ++t) {
        size_t row = (size_t)(b * TT + t0 + t);
        float dv = bf2f(deltab[row * EMBED + d]);
        float xv = bf2f(xcb[row * EMBED + d]);
        S += dv;
        float sx = dv * xv;
        float Bv[DSTATE];
        *(float4*)&Bv[0]  = *(const float4*)&Bs[t][0];
        *(float4*)&Bv[4]  = *(const float4*)&Bs[t][4];
        *(float4*)&Bv[8]  = *(const float4*)&Bs[t][8];
        *(float4*)&Bv[12] = *(const float4*)&Bs[t][12];
        #pragma unroll
        for (int n = 0; n < DSTATE; ++n) {
            float dA = __expf(dv * An[n]);
            h[n] = fmaf(dA, h[n], sx * Bv[n]);
        }
    }
    size_t base = ((size_t)(chunk * BB + b) * EMBED + d) * DSTATE;
    #pragma unroll
    for (int jj = 0; jj < 4; ++jj)
        *(float4*)&hout[base + jj * 4] = *(float4*)&h[jj * 4];
    Ssum[(size_t)(chunk * BB + b) * EMBED + d] = S;
}

// ---------------------------------------------------------------------------
// Scan pass B: combine over chunks; separate hin output + batch-8 prefetch
// ---------------------------------------------------------------------------
__global__ __launch_bounds__(256)
void scan_combine(const float* __restrict__ A_log,
                  const float* __restrict__ Ssum,
                  const float* __restrict__ hout,
                  float* __restrict__ hin)
{
    int idx = blockIdx.x * 256 + threadIdx.x;   // B*EMBED*DSTATE = 32768
    int n  = idx & 15;
    int bd = idx >> 4;
    float An = -__expf(A_log[n]);
    float h = 0.f;
    for (int c0 = 0; c0 < NCHUNK; c0 += 8) {
        float ho[8], S[8];
        #pragma unroll
        for (int jj = 0; jj < 8; ++jj) {
            ho[jj] = hout[(size_t)(c0 + jj) * (BB * EMBED * DSTATE) + idx];
            S[jj]  = Ssum[(size_t)(c0 + jj) * (BB * EMBED) + bd];
        }
        #pragma unroll
        for (int jj = 0; jj < 8; ++jj) {
            hin[(size_t)(c0 + jj) * (BB * EMBED * DSTATE) + idx] = h;
            h = fmaf(__expf(An * S[jj]), h, ho[jj]);
        }
    }
}

// ---------------------------------------------------------------------------
// Scan pass C: re-scan with h_in; n-reduction in regs; D skip; bf16 gate;
// write yb bf16 into Acat[:, 0:1024].  B/C from bc[m, 0:32].
// ---------------------------------------------------------------------------
__global__ __launch_bounds__(256)
void scan_apply(const unsigned short* __restrict__ deltab,
                const unsigned short* __restrict__ xcb,
                const float* __restrict__ bc,
                const float* __restrict__ A_log,
                const float* __restrict__ D_param,
                const unsigned short* __restrict__ gate,
                const float* __restrict__ hin,
                unsigned short* __restrict__ Acat)
{
    __shared__ float Bs[CLEN][DSTATE];
    __shared__ float Cs[CLEN][DSTATE];
    const int tid = threadIdx.x;
    const int blk = blockIdx.x;
    const int dg = blk & 3, chunk = (blk >> 2) & (NCHUNK - 1), b = blk >> 8;
    const int d = dg * 256 + tid;
    const int t0 = chunk * CLEN;

    for (int i = tid; i < CLEN * DSTATE; i += 256) {
        int t = i >> 4, n = i & 15;
        size_t row = (size_t)(b * TT + t0 + t);
        Bs[t][n] = bc[row * 32 + n];
        Cs[t][n] = bc[row * 32 + 16 + n];
    }
    __syncthreads();

    float An[DSTATE];
    #pragma unroll
    for (int n = 0; n < DSTATE; ++n) An[n] = -__expf(A_log[n]);
    float Dd = D_param[d];

    float h[DSTATE];
    size_t base = ((size_t)(chunk * BB + b) * EMBED + d) * DSTATE;
    #pragma unroll
    for (int jj = 0; jj < 4; ++jj)
        *(float4*)&h[jj * 4] = *(const float4*)&hin[base + jj * 4];

    for (int t = 0; t < CLEN; ++t) {
        size_t row = (size_t)(b * TT + t0 + t);
        float dv = bf2f(deltab[row * EMBED + d]);
        float xv = bf2f(xcb[row * EMBED + d]);
        float sx = dv * xv;
        float Bv[DSTATE], Cv[DSTATE];
        *(float4*)&Bv[0]  = *(const float4*)&Bs[t][0];
        *(float4*)&Bv[4]  = *(const float4*)&Bs[t][4];
        *(float4*)&Bv[8]  = *(const float4*)&Bs[t][8];
        *(float4*)&Bv[12] = *(const float4*)&Bs[t][12];
        *(float4*)&Cv[0]  = *(const float4*)&Cs[t][0];
        *(float4*)&Cv[4]  = *(const float4*)&Cs[t][4];
        *(float4*)&Cv[8]  = *(const float4*)&Cs[t][8];
        *(float4*)&Cv[12] = *(const float4*)&Cs[t][12];
        float y0 = 0.f, y1 = 0.f, y2 = 0.f, y3 = 0.f;
        #pragma unroll
        for (int n = 0; n < DSTATE; n += 4) {
            float dA0 = __expf(dv * An[n + 0]);
            float dA1 = __expf(dv * An[n + 1]);
            float dA2 = __expf(dv * An[n + 2]);
            float dA3 = __expf(dv * An[n + 3]);
            h[n + 0] = fmaf(dA0, h[n + 0], sx * Bv[n + 0]);
            h[n + 1] = fmaf(dA1, h[n + 1], sx * Bv[n + 1]);
            h[n + 2] = fmaf(dA2, h[n + 2], sx * Bv[n + 2]);
            h[n + 3] = fmaf(dA3, h[n + 3], sx * Bv[n + 3]);
            y0 = fmaf(h[n + 0], Cv[n + 0], y0);
            y1 = fmaf(h[n + 1], Cv[n + 1], y1);
            y2 = fmaf(h[n + 2], Cv[n + 2], y2);
            y3 = fmaf(h[n + 3], Cv[n + 3], y3);
        }
        float yv = (y0 + y1) + (y2 + y3) + xv * Dd;
        float g = bf2f(gate[row * EMBED + d]);
        Acat[row * 2 * EMBED + d] = f2bf(yv * g);
    }
}

// ---------------------------------------------------------------------------
extern "C" void kernel_launch(void* const* d_in, const int* in_sizes, int n_in,
                              void* d_out, int out_size, void* d_ws, size_t ws_size,
                              hipStream_t stream) {
    const float* x      = (const float*)d_in[0];
    const float* in_w   = (const float*)d_in[1];
    const float* in_b   = (const float*)d_in[2];
    const float* conv_w = (const float*)d_in[3];
    const float* conv_b = (const float*)d_in[4];
    const float* xp_w   = (const float*)d_in[5];
    const float* xp_b   = (const float*)d_in[6];
    const float* dt_w   = (const float*)d_in[7];
    const float* dt_b   = (const float*)d_in[8];
    const float* A_log  = (const float*)d_in[9];
    const float* Dp     = (const float*)d_in[10];
    const float* out_w  = (const float*)d_in[11];
    const float* out_b  = (const float*)d_in[12];
    const float* skip_w = (const float*)d_in[13];
    const float* skip_b = (const float*)d_in[14];
    float* out = (float*)d_out;

    // workspace layout (~75 MB)
    float* ws      = (float*)d_ws;
    float* bc      = ws;                                     // 4096*32
    float* biasm   = bc    + (size_t)M_TOK * 32;             // 1152
    float* hout    = biasm + 1152;                           // 64*2*1024*16
    float* hin     = hout  + (size_t)NCHUNK * BB * EMBED * DSTATE;
    float* Ssum    = hin   + (size_t)NCHUNK * BB * EMBED * DSTATE;  // 64*2*1024
    unsigned short* Acat = (unsigned short*)(Ssum + (size_t)NCHUNK * BB * EMBED);
    unsigned short* xrb  = Acat + (size_t)M_TOK * 2 * EMBED;
    unsigned short* xcb  = xrb  + (size_t)M_TOK * EMBED;
    unsigned short* dltb = xcb  + (size_t)M_TOK * EMBED;
    unsigned short* gate = dltb + (size_t)M_TOK * EMBED;
    unsigned short* inwb = gate + (size_t)M_TOK * EMBED;
    unsigned short* wcat = inwb + (size_t)2 * EMBED * EMBED;
    unsigned short* wmid = wcat + (size_t)2 * EMBED * EMBED;  // 1152*1024

    dim3 blk(256);

    // 0) pack weights + x; compute Wfuse + bias_mid
    cvt_pack<<<(SD + 255) / 256, blk, 0, stream>>>(
        in_w, xp_w, out_w, skip_w, x, inwb, wcat, Acat, wmid);
    wfuse_kernel<<<256, blk, 0, stream>>>(
        dt_w, xp_w, xp_b, dt_b, wmid, biasm);

    // 1) in_proj -> xrb bf16 (x_in) + gate bf16 (silu(res))
    gemm_in<<<dim3(M_TOK / 128, 2 * EMBED / 128), blk, 0, stream>>>(
        Acat + EMBED, inwb, in_b, xrb, gate);

    // 2) conv + silu -> xcb bf16
    conv_silu<<<(M_TOK * EMBED / 4 + 255) / 256, blk, 0, stream>>>(
        xrb, conv_w, conv_b, xcb);

    // 3) fused mid GEMM: delta (softplus, bf16) + B/C (fp32)
    gemm_mid<<<dim3(M_TOK / 128, NMID / 128), blk, 0, stream>>>(
        xcb, wmid, biasm, dltb, bc);

    // 4) selective scan (3 passes)
    scan_chunk<<<BB * NCHUNK * (EMBED / 256), blk, 0, stream>>>(
        dltb, xcb, bc, A_log, hout, Ssum);
    scan_combine<<<(BB * EMBED * DSTATE + 255) / 256, blk, 0, stream>>>(
        A_log, Ssum, hout, hin);
    scan_apply<<<BB * NCHUNK * (EMBED / 256), blk, 0, stream>>>(
        dltb, xcb, bc, A_log, Dp, gate, hin, Acat);

    // 5) fused out+skip GEMM (K=2048, direct store)
    gemm_out<<<dim3(M_TOK / 128, EMBED / 128), blk, 0, stream>>>(
        Acat, wcat, out_b, skip_b, out);
}

// Round 9
// 287.668 us; speedup vs baseline: 1.1233x; 1.1233x over previous
//
#include <hip/hip_runtime.h>
#include <math.h>

#define EMBED  1024
#define DSTATE 16
#define DCONV  4
#define DTRANK 64
#define BB     2
#define TT     2048
#define M_TOK  (BB*TT)      // 4096 token rows
#define NCHUNK 64
#define CLEN   (TT/NCHUNK)  // 32
#define NMID   1152         // 1024 delta + 32 B/C + 96 pad

typedef __attribute__((ext_vector_type(8))) __bf16 bf16x8;
typedef __attribute__((ext_vector_type(4))) float floatx4;

__device__ __forceinline__ float silu_f(float x) {
    return x / (1.0f + __expf(-x));
}
// fast softplus: no log1pf libcall; exact to ~1e-7 (plenty for bf16 out)
__device__ __forceinline__ float softplus_f(float x) {
    return (x > 15.0f) ? x : __logf(1.0f + __expf(x));
}
__device__ __forceinline__ unsigned short f2bf(float f) {
    union { float f; unsigned int u; } v; v.f = f;
    unsigned int u = v.u;
    return (unsigned short)((u + 0x7fffu + ((u >> 16) & 1u)) >> 16);
}
__device__ __forceinline__ float bf2f(unsigned short s) {
    union { unsigned int u; float f; } v; v.u = ((unsigned int)s) << 16;
    return v.f;
}
__device__ __forceinline__ void async16(unsigned short* lds, const unsigned short* g) {
    __builtin_amdgcn_global_load_lds(
        (const __attribute__((address_space(1))) unsigned int*)g,
        (__attribute__((address_space(3))) unsigned int*)lds, 16, 0, 0);
}

// decode helper for the 2x2-wave 128x128 tile
#define GEMM_DECODE \
    const int tid = threadIdx.x; const int wid = tid >> 6; \
    const int lane = tid & 63; \
    const int wm = wid >> 1, wn = wid & 1; \
    const int lr = lane & 15; const int lq = lane >> 4;

// ---------------------------------------------------------------------------
// MFMA core: 128x128 tile, BK=32, 256 thr = 4 waves (2x2), 4x4 16x16x32/wave.
// XOR-swizzled LDS (verified R6: SQ_LDS_BANK_CONFLICT -> 0).
// ---------------------------------------------------------------------------
__device__ __forceinline__ void gemm_acc(
    const unsigned short* __restrict__ A, int lda,
    const unsigned short* __restrict__ W, int ldw,
    int m0, int n0, int k0, int klen, floatx4 (&acc)[4][4])
{
    __shared__ unsigned short As[128 * 32];
    __shared__ unsigned short Ws[128 * 32];
    GEMM_DECODE;
    const int l0 = tid,       row0 = l0 >> 2;
    const int l1 = tid + 256, row1 = l1 >> 2;
    const int kc0 = (((l0 & 3) ^ ((row0 >> 1) & 3)) * 8);
    const int kc1 = (((l1 & 3) ^ ((row1 >> 1) & 3)) * 8);

    for (int kt = k0; kt < k0 + klen; kt += 32) {
        async16(&As[l0 * 8], A + (size_t)(m0 + row0) * lda + kt + kc0);
        async16(&As[l1 * 8], A + (size_t)(m0 + row1) * lda + kt + kc1);
        async16(&Ws[l0 * 8], W + (size_t)(n0 + row0) * ldw + kt + kc0);
        async16(&Ws[l1 * 8], W + (size_t)(n0 + row1) * ldw + kt + kc1);
        __syncthreads();

        bf16x8 af[4], bfr[4];
        #pragma unroll
        for (int i = 0; i < 4; ++i) {
            int ra = wm * 64 + i * 16 + lr;
            af[i] = *(const bf16x8*)&As[ra * 32 + ((lq ^ ((ra >> 1) & 3)) * 8)];
        }
        #pragma unroll
        for (int i = 0; i < 4; ++i) {
            int rb = wn * 64 + i * 16 + lr;
            bfr[i] = *(const bf16x8*)&Ws[rb * 32 + ((lq ^ ((rb >> 1) & 3)) * 8)];
        }

        #pragma unroll
        for (int mi = 0; mi < 4; ++mi)
            #pragma unroll
            for (int ni = 0; ni < 4; ++ni)
                acc[mi][ni] = __builtin_amdgcn_mfma_f32_16x16x32_bf16(
                    af[mi], bfr[ni], acc[mi][ni], 0, 0, 0);
        __syncthreads();
    }
}

// ---------------------------------------------------------------------------
// in_proj: x @ in_w^T + b.  n<1024 -> xrb bf16 (conv input);
//          n>=1024 -> gate = silu(res) bf16.  grid (32, 16)
// ---------------------------------------------------------------------------
__global__ __launch_bounds__(256)
void gemm_in(const unsigned short* __restrict__ A,
             const unsigned short* __restrict__ W,
             const float* __restrict__ bias,
             unsigned short* __restrict__ xrb, unsigned short* __restrict__ gate)
{
    floatx4 acc[4][4] = {};
    const int m0 = blockIdx.x * 128, n0 = blockIdx.y * 128;
    gemm_acc(A, 2 * EMBED, W, EMBED, m0, n0, 0, EMBED, acc);
    GEMM_DECODE;
    #pragma unroll
    for (int mi = 0; mi < 4; ++mi)
        #pragma unroll
        for (int ni = 0; ni < 4; ++ni) {
            int nb = n0 + wn * 64 + ni * 16 + lr;
            #pragma unroll
            for (int r = 0; r < 4; ++r) {
                int m = m0 + wm * 64 + mi * 16 + lq * 4 + r;
                float v = acc[mi][ni][r] + bias[nb];
                if (nb < EMBED) xrb[(size_t)m * EMBED + nb] = f2bf(v);
                else gate[(size_t)m * EMBED + nb - EMBED] = f2bf(silu_f(v));
            }
        }
}

// ---------------------------------------------------------------------------
// Wfuse precompute (throughput version): Wfuse[d,k] = sum_r dt_w[d,r]*xp_w[r,k]
// grid 256 blocks; block handles 4 d-rows; thread t owns k-cols [4t, 4t+4).
// Each xp_w float4 load feeds 16 fmaf (4 d-rows) — L2 traffic /4 vs R8;
// r-loop unroll 8 keeps 8 independent loads in flight (R8 had ~4, serial).
// ---------------------------------------------------------------------------
__global__ __launch_bounds__(256)
void wfuse_kernel(const float* __restrict__ dt_w, const float* __restrict__ xp_w,
                  const float* __restrict__ xp_b, const float* __restrict__ dt_b,
                  unsigned short* __restrict__ wmid, float* __restrict__ bias_mid)
{
    __shared__ float dtl[4][64];
    const int t = threadIdx.x;
    const int d0 = blockIdx.x * 4;
    dtl[t >> 6][t & 63] = dt_w[(size_t)(d0 + (t >> 6)) * DTRANK + (t & 63)];
    __syncthreads();

    const int k4 = t * 4;
    float4 acc0 = {0.f,0.f,0.f,0.f}, acc1 = {0.f,0.f,0.f,0.f};
    float4 acc2 = {0.f,0.f,0.f,0.f}, acc3 = {0.f,0.f,0.f,0.f};

    #pragma unroll 8
    for (int r = 0; r < 64; ++r) {
        float4 xv = *(const float4*)&xp_w[(size_t)r * EMBED + k4];
        float s0 = dtl[0][r], s1 = dtl[1][r], s2 = dtl[2][r], s3 = dtl[3][r];
        acc0.x = fmaf(s0, xv.x, acc0.x); acc0.y = fmaf(s0, xv.y, acc0.y);
        acc0.z = fmaf(s0, xv.z, acc0.z); acc0.w = fmaf(s0, xv.w, acc0.w);
        acc1.x = fmaf(s1, xv.x, acc1.x); acc1.y = fmaf(s1, xv.y, acc1.y);
        acc1.z = fmaf(s1, xv.z, acc1.z); acc1.w = fmaf(s1, xv.w, acc1.w);
        acc2.x = fmaf(s2, xv.x, acc2.x); acc2.y = fmaf(s2, xv.y, acc2.y);
        acc2.z = fmaf(s2, xv.z, acc2.z); acc2.w = fmaf(s2, xv.w, acc2.w);
        acc3.x = fmaf(s3, xv.x, acc3.x); acc3.y = fmaf(s3, xv.y, acc3.y);
        acc3.z = fmaf(s3, xv.z, acc3.z); acc3.w = fmaf(s3, xv.w, acc3.w);
    }

    ushort4 o0 = { f2bf(acc0.x), f2bf(acc0.y), f2bf(acc0.z), f2bf(acc0.w) };
    ushort4 o1 = { f2bf(acc1.x), f2bf(acc1.y), f2bf(acc1.z), f2bf(acc1.w) };
    ushort4 o2 = { f2bf(acc2.x), f2bf(acc2.y), f2bf(acc2.z), f2bf(acc2.w) };
    ushort4 o3 = { f2bf(acc3.x), f2bf(acc3.y), f2bf(acc3.z), f2bf(acc3.w) };
    *(ushort4*)&wmid[(size_t)(d0 + 0) * EMBED + k4] = o0;
    *(ushort4*)&wmid[(size_t)(d0 + 1) * EMBED + k4] = o1;
    *(ushort4*)&wmid[(size_t)(d0 + 2) * EMBED + k4] = o2;
    *(ushort4*)&wmid[(size_t)(d0 + 3) * EMBED + k4] = o3;

    if (t < 4) {
        float b = dt_b[d0 + t];
        #pragma unroll 8
        for (int r = 0; r < 64; ++r) b = fmaf(dtl[t][r], xp_b[r], b);
        bias_mid[d0 + t] = b;
    }
    if (blockIdx.x == 0 && t >= 128 && t < 256) {
        int j = t - 128;
        bias_mid[1024 + j] = (j < 32) ? xp_b[DTRANK + j] : 0.f;
    }
}

// ---------------------------------------------------------------------------
// fused mid GEMM: xc @ wmid^T + bias_mid.  grid (32, 9), K=1024.
//   nb < 1024  -> delta = softplus -> dltb bf16
//   1024..1055 -> B/C fp32 -> bc[m, 0:32]  (B = 0:16, C = 16:32)
// ---------------------------------------------------------------------------
__global__ __launch_bounds__(256)
void gemm_mid(const unsigned short* __restrict__ A,
              const unsigned short* __restrict__ W,
              const float* __restrict__ bias_mid,
              unsigned short* __restrict__ dltb, float* __restrict__ bc)
{
    floatx4 acc[4][4] = {};
    const int m0 = blockIdx.x * 128, n0 = blockIdx.y * 128;
    gemm_acc(A, EMBED, W, EMBED, m0, n0, 0, EMBED, acc);
    GEMM_DECODE;
    #pragma unroll
    for (int mi = 0; mi < 4; ++mi)
        #pragma unroll
        for (int ni = 0; ni < 4; ++ni) {
            int nb = n0 + wn * 64 + ni * 16 + lr;
            float bb = bias_mid[nb];
            #pragma unroll
            for (int r = 0; r < 4; ++r) {
                int m = m0 + wm * 64 + mi * 16 + lq * 4 + r;
                float v = acc[mi][ni][r] + bb;
                if (nb < 1024) dltb[(size_t)m * EMBED + nb] = f2bf(softplus_f(v));
                else if (nb < 1056) bc[(size_t)m * 32 + nb - 1024] = v;
            }
        }
}

// ---------------------------------------------------------------------------
// fused out+skip: [yb|x] @ [ow|sw]^T + ob + sb.  grid (32, 8), K=2048
// ---------------------------------------------------------------------------
__global__ __launch_bounds__(256)
void gemm_out(const unsigned short* __restrict__ A,
              const unsigned short* __restrict__ W,
              const float* __restrict__ bias, const float* __restrict__ bias2,
              float* __restrict__ C)
{
    floatx4 acc[4][4] = {};
    const int m0 = blockIdx.x * 128, n0 = blockIdx.y * 128;
    gemm_acc(A, 2 * EMBED, W, 2 * EMBED, m0, n0, 0, 2 * EMBED, acc);
    GEMM_DECODE;
    #pragma unroll
    for (int mi = 0; mi < 4; ++mi)
        #pragma unroll
        for (int ni = 0; ni < 4; ++ni) {
            int nb = n0 + wn * 64 + ni * 16 + lr;
            float bb = bias[nb] + bias2[nb];
            #pragma unroll
            for (int r = 0; r < 4; ++r) {
                int m = m0 + wm * 64 + mi * 16 + lq * 4 + r;
                C[(size_t)m * EMBED + nb] = acc[mi][ni][r] + bb;
            }
        }
}

// ---------------------------------------------------------------------------
// single fused pack kernel (float4 units):
//   [0, SA)      in_w -> inwb
//   [SA, SB)     [out_w|skip_w] -> wcat
//   [SB, SC)     x -> Acat[:, 1024:2048]
//   [SC, SD)     wmid rows 1024..1151: 32 B/C rows from xp_w[64:96], 96 zero
// ---------------------------------------------------------------------------
#define SA 524288
#define SB (SA + 524288)
#define SC (SB + 1048576)
#define SD (SC + 32768)

__global__ __launch_bounds__(256)
void cvt_pack(const float* __restrict__ in_w, const float* __restrict__ xp_w,
              const float* __restrict__ ow, const float* __restrict__ sw,
              const float* __restrict__ x,
              unsigned short* __restrict__ inwb, unsigned short* __restrict__ wcat,
              unsigned short* __restrict__ Acat, unsigned short* __restrict__ wmid)
{
    int j = blockIdx.x * 256 + threadIdx.x;
    if (j >= SD) return;
    float4 v = {0.f, 0.f, 0.f, 0.f};
    unsigned short* dst;
    if (j < SA) {
        v = *(const float4*)&in_w[j * 4];
        dst = &inwb[j * 4];
    } else if (j < SB) {
        int i = (j - SA) * 4;
        int n = i >> 11, k = i & 2047;
        v = *(const float4*)((k < EMBED) ? &ow[(size_t)n * EMBED + k]
                                         : &sw[(size_t)n * EMBED + (k - EMBED)]);
        dst = &wcat[i];
    } else if (j < SC) {
        int i = (j - SB) * 4;
        int m = i >> 10, k = i & 1023;
        v = *(const float4*)&x[i];
        dst = &Acat[(size_t)m * 2 * EMBED + EMBED + k];
    } else {
        int i = (j - SC) * 4;          // over 128*1024
        int row = i >> 10, k = i & 1023;
        if (row < 32) v = *(const float4*)&xp_w[(size_t)(DTRANK + row) * EMBED + k];
        dst = &wmid[(size_t)(1024 + row) * EMBED + k];
    }
    ushort4 o = { f2bf(v.x), f2bf(v.y), f2bf(v.z), f2bf(v.w) };
    *(ushort4*)dst = o;
}

// ---------------------------------------------------------------------------
// depthwise causal conv1d (k=4) + bias + SiLU -> xc bf16; 4 channels/thread
// ---------------------------------------------------------------------------
__global__ __launch_bounds__(256)
void conv_silu(const unsigned short* __restrict__ xrb,
               const float* __restrict__ conv_w,
               const float* __restrict__ conv_b,
               unsigned short* __restrict__ xcb)
{
    int idx = blockIdx.x * 256 + threadIdx.x;     // over B*T*D/4 = 1M
    if (idx >= BB * TT * EMBED / 4) return;
    int dq = idx & (EMBED / 4 - 1);
    int t  = (idx >> 8) & (TT - 1);
    int b  = idx >> 19;
    int d  = dq * 4;

    float4 cw0 = *(const float4*)&conv_w[(d + 0) * 4];
    float4 cw1 = *(const float4*)&conv_w[(d + 1) * 4];
    float4 cw2 = *(const float4*)&conv_w[(d + 2) * 4];
    float4 cw3 = *(const float4*)&conv_w[(d + 3) * 4];
    float4 s   = *(const float4*)&conv_b[d];

    const float* w0 = (const float*)&cw0;
    const float* w1 = (const float*)&cw1;
    const float* w2 = (const float*)&cw2;
    const float* w3 = (const float*)&cw3;

    #pragma unroll
    for (int jj = 0; jj < 4; ++jj) {
        int tr = t - 3 + jj;
        if (tr >= 0) {
            ushort4 u = *(const ushort4*)&xrb[(size_t)(b * TT + tr) * EMBED + d];
            s.x = fmaf(w0[jj], bf2f(u.x), s.x);
            s.y = fmaf(w1[jj], bf2f(u.y), s.y);
            s.z = fmaf(w2[jj], bf2f(u.z), s.z);
            s.w = fmaf(w3[jj], bf2f(u.w), s.w);
        }
    }
    ushort4 o = { f2bf(silu_f(s.x)), f2bf(silu_f(s.y)),
                  f2bf(silu_f(s.z)), f2bf(silu_f(s.w)) };
    *(ushort4*)&xcb[(size_t)(b * TT + t) * EMBED + d] = o;
}

// ---------------------------------------------------------------------------
// Scan pass A: thread per (b,chunk,d), 16 states in regs. B from bc[m,0:16].
// ---------------------------------------------------------------------------
__global__ __launch_bounds__(256)
void scan_chunk(const unsigned short* __restrict__ deltab,
                const unsigned short* __restrict__ xcb,
                const float* __restrict__ bc,
                const float* __restrict__ A_log,
                float* __restrict__ hout,
                float* __restrict__ Ssum)
{
    __shared__ float Bs[CLEN][DSTATE];
    const int tid = threadIdx.x;
    const int blk = blockIdx.x;
    const int dg = blk & 3, chunk = (blk >> 2) & (NCHUNK - 1), b = blk >> 8;
    const int d = dg * 256 + tid;
    const int t0 = chunk * CLEN;

    for (int i = tid; i < CLEN * DSTATE; i += 256) {
        int t = i >> 4, n = i & 15;
        Bs[t][n] = bc[(size_t)(b * TT + t0 + t) * 32 + n];
    }
    __syncthreads();

    float An[DSTATE];
    #pragma unroll
    for (int n = 0; n < DSTATE; ++n) An[n] = -__expf(A_log[n]);

    float h[DSTATE] = {};
    float S = 0.f;
    for (int t = 0; t < CLEN; ++t) {
        size_t row = (size_t)(b * TT + t0 + t);
        float dv = bf2f(deltab[row * EMBED + d]);
        float xv = bf2f(xcb[row * EMBED + d]);
        S += dv;
        float sx = dv * xv;
        float Bv[DSTATE];
        *(float4*)&Bv[0]  = *(const float4*)&Bs[t][0];
        *(float4*)&Bv[4]  = *(const float4*)&Bs[t][4];
        *(float4*)&Bv[8]  = *(const float4*)&Bs[t][8];
        *(float4*)&Bv[12] = *(const float4*)&Bs[t][12];
        #pragma unroll
        for (int n = 0; n < DSTATE; ++n) {
            float dA = __expf(dv * An[n]);
            h[n] = fmaf(dA, h[n], sx * Bv[n]);
        }
    }
    size_t base = ((size_t)(chunk * BB + b) * EMBED + d) * DSTATE;
    #pragma unroll
    for (int jj = 0; jj < 4; ++jj)
        *(float4*)&hout[base + jj * 4] = *(float4*)&h[jj * 4];
    Ssum[(size_t)(chunk * BB + b) * EMBED + d] = S;
}

// ---------------------------------------------------------------------------
// Scan pass B: combine over chunks; separate hin output + batch-8 prefetch
// ---------------------------------------------------------------------------
__global__ __launch_bounds__(256)
void scan_combine(const float* __restrict__ A_log,
                  const float* __restrict__ Ssum,
                  const float* __restrict__ hout,
                  float* __restrict__ hin)
{
    int idx = blockIdx.x * 256 + threadIdx.x;   // B*EMBED*DSTATE = 32768
    int n  = idx & 15;
    int bd = idx >> 4;
    float An = -__expf(A_log[n]);
    float h = 0.f;
    for (int c0 = 0; c0 < NCHUNK; c0 += 8) {
        float ho[8], S[8];
        #pragma unroll
        for (int jj = 0; jj < 8; ++jj) {
            ho[jj] = hout[(size_t)(c0 + jj) * (BB * EMBED * DSTATE) + idx];
            S[jj]  = Ssum[(size_t)(c0 + jj) * (BB * EMBED) + bd];
        }
        #pragma unroll
        for (int jj = 0; jj < 8; ++jj) {
            hin[(size_t)(c0 + jj) * (BB * EMBED * DSTATE) + idx] = h;
            h = fmaf(__expf(An * S[jj]), h, ho[jj]);
        }
    }
}

// ---------------------------------------------------------------------------
// Scan pass C: re-scan with h_in; n-reduction in regs; D skip; bf16 gate;
// write yb bf16 into Acat[:, 0:1024].  B/C from bc[m, 0:32].
// ---------------------------------------------------------------------------
__global__ __launch_bounds__(256)
void scan_apply(const unsigned short* __restrict__ deltab,
                const unsigned short* __restrict__ xcb,
                const float* __restrict__ bc,
                const float* __restrict__ A_log,
                const float* __restrict__ D_param,
                const unsigned short* __restrict__ gate,
                const float* __restrict__ hin,
                unsigned short* __restrict__ Acat)
{
    __shared__ float Bs[CLEN][DSTATE];
    __shared__ float Cs[CLEN][DSTATE];
    const int tid = threadIdx.x;
    const int blk = blockIdx.x;
    const int dg = blk & 3, chunk = (blk >> 2) & (NCHUNK - 1), b = blk >> 8;
    const int d = dg * 256 + tid;
    const int t0 = chunk * CLEN;

    for (int i = tid; i < CLEN * DSTATE; i += 256) {
        int t = i >> 4, n = i & 15;
        size_t row = (size_t)(b * TT + t0 + t);
        Bs[t][n] = bc[row * 32 + n];
        Cs[t][n] = bc[row * 32 + 16 + n];
    }
    __syncthreads();

    float An[DSTATE];
    #pragma unroll
    for (int n = 0; n < DSTATE; ++n) An[n] = -__expf(A_log[n]);
    float Dd = D_param[d];

    float h[DSTATE];
    size_t base = ((size_t)(chunk * BB + b) * EMBED + d) * DSTATE;
    #pragma unroll
    for (int jj = 0; jj < 4; ++jj)
        *(float4*)&h[jj * 4] = *(const float4*)&hin[base + jj * 4];

    for (int t = 0; t < CLEN; ++t) {
        size_t row = (size_t)(b * TT + t0 + t);
        float dv = bf2f(deltab[row * EMBED + d]);
        float xv = bf2f(xcb[row * EMBED + d]);
        float sx = dv * xv;
        float Bv[DSTATE], Cv[DSTATE];
        *(float4*)&Bv[0]  = *(const float4*)&Bs[t][0];
        *(float4*)&Bv[4]  = *(const float4*)&Bs[t][4];
        *(float4*)&Bv[8]  = *(const float4*)&Bs[t][8];
        *(float4*)&Bv[12] = *(const float4*)&Bs[t][12];
        *(float4*)&Cv[0]  = *(const float4*)&Cs[t][0];
        *(float4*)&Cv[4]  = *(const float4*)&Cs[t][4];
        *(float4*)&Cv[8]  = *(const float4*)&Cs[t][8];
        *(float4*)&Cv[12] = *(const float4*)&Cs[t][12];
        float y0 = 0.f, y1 = 0.f, y2 = 0.f, y3 = 0.f;
        #pragma unroll
        for (int n = 0; n < DSTATE; n += 4) {
            float dA0 = __expf(dv * An[n + 0]);
            float dA1 = __expf(dv * An[n + 1]);
            float dA2 = __expf(dv * An[n + 2]);
            float dA3 = __expf(dv * An[n + 3]);
            h[n + 0] = fmaf(dA0, h[n + 0], sx * Bv[n + 0]);
            h[n + 1] = fmaf(dA1, h[n + 1], sx * Bv[n + 1]);
            h[n + 2] = fmaf(dA2, h[n + 2], sx * Bv[n + 2]);
            h[n + 3] = fmaf(dA3, h[n + 3], sx * Bv[n + 3]);
            y0 = fmaf(h[n + 0], Cv[n + 0], y0);
            y1 = fmaf(h[n + 1], Cv[n + 1], y1);
            y2 = fmaf(h[n + 2], Cv[n + 2], y2);
            y3 = fmaf(h[n + 3], Cv[n + 3], y3);
        }
        float yv = (y0 + y1) + (y2 + y3) + xv * Dd;
        float g = bf2f(gate[row * EMBED + d]);
        Acat[row * 2 * EMBED + d] = f2bf(yv * g);
    }
}

// ---------------------------------------------------------------------------
extern "C" void kernel_launch(void* const* d_in, const int* in_sizes, int n_in,
                              void* d_out, int out_size, void* d_ws, size_t ws_size,
                              hipStream_t stream) {
    const float* x      = (const float*)d_in[0];
    const float* in_w   = (const float*)d_in[1];
    const float* in_b   = (const float*)d_in[2];
    const float* conv_w = (const float*)d_in[3];
    const float* conv_b = (const float*)d_in[4];
    const float* xp_w   = (const float*)d_in[5];
    const float* xp_b   = (const float*)d_in[6];
    const float* dt_w   = (const float*)d_in[7];
    const float* dt_b   = (const float*)d_in[8];
    const float* A_log  = (const float*)d_in[9];
    const float* Dp     = (const float*)d_in[10];
    const float* out_w  = (const float*)d_in[11];
    const float* out_b  = (const float*)d_in[12];
    const float* skip_w = (const float*)d_in[13];
    const float* skip_b = (const float*)d_in[14];
    float* out = (float*)d_out;

    // workspace layout (~75 MB)
    float* ws      = (float*)d_ws;
    float* bc      = ws;                                     // 4096*32
    float* biasm   = bc    + (size_t)M_TOK * 32;             // 1152
    float* hout    = biasm + 1152;                           // 64*2*1024*16
    float* hin     = hout  + (size_t)NCHUNK * BB * EMBED * DSTATE;
    float* Ssum    = hin   + (size_t)NCHUNK * BB * EMBED * DSTATE;  // 64*2*1024
    unsigned short* Acat = (unsigned short*)(Ssum + (size_t)NCHUNK * BB * EMBED);
    unsigned short* xrb  = Acat + (size_t)M_TOK * 2 * EMBED;
    unsigned short* xcb  = xrb  + (size_t)M_TOK * EMBED;
    unsigned short* dltb = xcb  + (size_t)M_TOK * EMBED;
    unsigned short* gate = dltb + (size_t)M_TOK * EMBED;
    unsigned short* inwb = gate + (size_t)M_TOK * EMBED;
    unsigned short* wcat = inwb + (size_t)2 * EMBED * EMBED;
    unsigned short* wmid = wcat + (size_t)2 * EMBED * EMBED;  // 1152*1024

    dim3 blk(256);

    // 0) pack weights + x; compute Wfuse + bias_mid
    cvt_pack<<<(SD + 255) / 256, blk, 0, stream>>>(
        in_w, xp_w, out_w, skip_w, x, inwb, wcat, Acat, wmid);
    wfuse_kernel<<<256, blk, 0, stream>>>(
        dt_w, xp_w, xp_b, dt_b, wmid, biasm);

    // 1) in_proj -> xrb bf16 (x_in) + gate bf16 (silu(res))
    gemm_in<<<dim3(M_TOK / 128, 2 * EMBED / 128), blk, 0, stream>>>(
        Acat + EMBED, inwb, in_b, xrb, gate);

    // 2) conv + silu -> xcb bf16
    conv_silu<<<(M_TOK * EMBED / 4 + 255) / 256, blk, 0, stream>>>(
        xrb, conv_w, conv_b, xcb);

    // 3) fused mid GEMM: delta (softplus, bf16) + B/C (fp32)
    gemm_mid<<<dim3(M_TOK / 128, NMID / 128), blk, 0, stream>>>(
        xcb, wmid, biasm, dltb, bc);

    // 4) selective scan (3 passes)
    scan_chunk<<<BB * NCHUNK * (EMBED / 256), blk, 0, stream>>>(
        dltb, xcb, bc, A_log, hout, Ssum);
    scan_combine<<<(BB * EMBED * DSTATE + 255) / 256, blk, 0, stream>>>(
        A_log, Ssum, hout, hin);
    scan_apply<<<BB * NCHUNK * (EMBED / 256), blk, 0, stream>>>(
        dltb, xcb, bc, A_log, Dp, gate, hin, Acat);

    // 5) fused out+skip GEMM (K=2048, direct store)
    gemm_out<<<dim3(M_TOK / 128, EMBED / 128), blk, 0, stream>>>(
        Acat, wcat, out_b, skip_b, out);
}